// Round 33
// baseline (146.670 us; speedup 1.0000x reference)
//
#include <hip/hip_runtime.h>
#include <hip/hip_fp16.h>
#include <math.h>

#define NRAYS 1024
#define NSAMP 512
#define GRIDN 300
#define POS_ELEMS (GRIDN*GRIDN)
#define PLANE_ELEMS (16*POS_ELEMS)
#define CMAX 524288

typedef short bf16x8 __attribute__((ext_vector_type(8)));
typedef short short8 __attribute__((ext_vector_type(8)));
typedef float f32x4  __attribute__((ext_vector_type(4)));

struct H8v { __half2 h[4]; };    // 8 fp16 = 16B

__device__ __forceinline__ float clampf(float x, float a, float b){ return fminf(fmaxf(x,a),b); }
__device__ __forceinline__ unsigned short f2b(float f){
    unsigned u = __builtin_bit_cast(unsigned, f);
    u = (u + 0x7FFFu + ((u>>16)&1u)) >> 16;
    return (unsigned short)u;
}
__device__ __forceinline__ float b2f(unsigned short h){
    unsigned u = ((unsigned)h) << 16;
    return __builtin_bit_cast(float, u);
}

__device__ __forceinline__ float ray_tmin(float o0,float o1,float o2,float d0,float d1,float d2){
    float v0=(d0==0.f)?1e-6f:d0, v1=(d1==0.f)?1e-6f:d1, v2=(d2==0.f)?1e-6f:d2;
    float t_min = -1e30f, a, b;
    a=(1.5f-o0)/v0; b=(-1.5f-o0)/v0; t_min=fmaxf(t_min,fminf(a,b));
    a=(1.5f-o1)/v1; b=(-1.5f-o1)/v1; t_min=fmaxf(t_min,fminf(a,b));
    a=(1.5f-o2)/v2; b=(-1.5f-o2)/v2; t_min=fmaxf(t_min,fminf(a,b));
    return clampf(t_min, 2.0f, 6.0f);
}

// ---------------------------------------------------------------- transpose: planes/lines -> channel-last fp16; by==6 slice does weight prep
struct TPtrs {
    const float* psrc[6]; __half* pdst[6];
    const float* lsrc[6]; __half* ldst[6];
};

__global__ __launch_bounds__(256) void k_transpose(TPtrs tp,
    const float* __restrict__ w1, const float* __restrict__ w2,
    unsigned short* __restrict__ w1b, unsigned short* __restrict__ w2b)
{
    int by  = blockIdx.y;
    if (by == 6) {                 // fused weight prep (144 blocks active)
        int idx = blockIdx.x * 256 + threadIdx.x;
        if (idx < 128*160) {
            int j = idx / 160, k = idx - j*160;
            w1b[idx] = (k < 150) ? f2b(w1[j*150 + k]) : 0;
        } else if (idx < 128*160 + 128*128) {
            int i2 = idx - 128*160;
            w2b[i2] = f2b(w2[i2]);
        }
        return;
    }
    int pos = blockIdx.x * 256 + threadIdx.x;
    if (pos < POS_ELEMS) {
        const float* src = tp.psrc[by];
        __half2 o[8];
        #pragma unroll
        for (int e = 0; e < 8; e++) {
            float a = src[(2*e  ) * POS_ELEMS + pos];
            float b = src[(2*e+1) * POS_ELEMS + pos];
            o[e] = __float22half2_rn(make_float2(a,b));
        }
        float4* dst = (float4*)(tp.pdst[by] + (size_t)pos * 16);
        dst[0] = *(float4*)&o[0];
        dst[1] = *(float4*)&o[4];
    }
    if (pos < GRIDN) {
        const float* ls = tp.lsrc[by];
        __half*      ld = tp.ldst[by];
        #pragma unroll
        for (int c = 0; c < 16; c++) ld[pos * 16 + c] = __float2half_rn(ls[c * GRIDN + pos]);
    }
}

// ---------------------------------------------------------------- k_alphascan: alpha (1024 thr: sample x half) + per-ray scan/compaction fused
__global__ __launch_bounds__(1024) void k_alphascan(
    const float* __restrict__ ro, const float* __restrict__ rd,
    const __half* __restrict__ dpT0, const __half* __restrict__ dpT1, const __half* __restrict__ dpT2,
    const __half* __restrict__ dlT0, const __half* __restrict__ dlT1, const __half* __restrict__ dlT2,
    float* __restrict__ acc_out, float* __restrict__ depth_out,
    int* __restrict__ tmpl, float* __restrict__ tmpw, int* __restrict__ cnt)
{
    const float STEPF = (3.0f/299.0f)*0.5f;
    int r = blockIdx.x;
    int tid = threadIdx.x;
    int s = tid >> 1, h = tid & 1;

    __shared__ float alpha_s[NSAMP];
    __shared__ float wtot[4], swsum[4], sdep[4];
    __shared__ int   wcnt[4];

    float o0=ro[r*3+0], o1=ro[r*3+1], o2=ro[r*3+2];
    float d0=rd[r*3+0], d1=rd[r*3+1], d2=rd[r*3+2];
    float t_min = ray_tmin(o0,o1,o2,d0,d1,d2);

    // ---- alpha phase (all 1024 threads; 2 threads per sample = channel halves)
    {
        float z  = t_min + STEPF * (float)s;
        float p0 = o0 + d0*z, p1 = o1 + d1*z, p2 = o2 + d2*z;
        bool valid = (p0>=-1.5f)&&(p0<=1.5f)&&(p1>=-1.5f)&&(p1<=1.5f)&&(p2>=-1.5f)&&(p2<=1.5f);

        float sfp = 0.f;
        if (valid) {
            float xn[3] = { (p0+1.5f)*(2.0f/3.0f)-1.0f,
                            (p1+1.5f)*(2.0f/3.0f)-1.0f,
                            (p2+1.5f)*(2.0f/3.0f)-1.0f };
            const __half* dpT[3] = {dpT0,dpT1,dpT2};
            const __half* dlT[3] = {dlT0,dlT1,dlT2};
            const int M0[3]={0,0,1}, M1[3]={1,2,2}, V[3]={2,1,0};
            #pragma unroll
            for (int i=0;i<3;i++) {
                float fx = clampf((xn[M0[i]]*0.5f+0.5f)*299.f, 0.f, 299.f);
                float fy = clampf((xn[M1[i]]*0.5f+0.5f)*299.f, 0.f, 299.f);
                float ft = clampf((xn[V[i]] *0.5f+0.5f)*299.f, 0.f, 299.f);
                int x0=min((int)fx,298), y0=min((int)fy,298), i0=min((int)ft,298);
                float wx=fx-(float)x0, wy=fy-(float)y0, wt=ft-(float)i0;
                __half2 w00=__float2half2_rn((1.f-wx)*(1.f-wy)), w01=__float2half2_rn(wx*(1.f-wy));
                __half2 w10=__float2half2_rn((1.f-wx)*wy),       w11=__float2half2_rn(wx*wy);
                __half2 u0 =__float2half2_rn(1.f-wt),            u1 =__float2half2_rn(wt);
                const __half* base = dpT[i] + (size_t)(y0*GRIDN+x0)*16 + h*8;
                H8v a00 = *(const H8v*)(base);
                H8v a01 = *(const H8v*)(base + 16);
                H8v a10 = *(const H8v*)(base + GRIDN*16);
                H8v a11 = *(const H8v*)(base + GRIDN*16 + 16);
                const __half* lb = dlT[i] + (size_t)i0*16 + h*8;
                H8v l0 = *(const H8v*)(lb);
                H8v l1 = *(const H8v*)(lb + 16);
                #pragma unroll
                for (int e=0;e<4;e++) {
                    __half2 p = __hmul2(a00.h[e],w00);
                    p = __hfma2(a01.h[e],w01,p);
                    p = __hfma2(a10.h[e],w10,p);
                    p = __hfma2(a11.h[e],w11,p);
                    __half2 l = __hmul2(l0.h[e],u0);
                    l = __hfma2(l1.h[e],u1,l);
                    float2 c = __half22float2(__hmul2(p,l));
                    sfp += c.x + c.y;
                }
            }
        }
        float sf = sfp + __shfl_xor(sfp, 1, 64);   // combine halves (adjacent lanes)
        if (h == 0) {
            float sig = 0.f;
            if (valid) {
                float xs = sf - 10.0f;
                sig = fmaxf(xs, 0.f) + __logf(1.f + __expf(-fabsf(xs)));   // softplus
            }
            alpha_s[s] = (s < NSAMP-1) ? (1.f - __expf(-sig * (STEPF*25.0f))) : 0.f;
        }
    }
    __syncthreads();

    // ---- scan phase (first 256 threads; barriers are block-wide)
    int lane = tid & 63, wv = tid >> 6;
    float aj0=0.f, aj1=0.f, zj0=0.f, zj1=0.f, inc=1.f, v0=1.f, v1=1.f;
    if (tid < 256) {
        aj0 = alpha_s[2*tid]; aj1 = alpha_s[2*tid+1];
        zj0 = t_min + STEPF * (float)(2*tid);
        zj1 = t_min + STEPF * (float)(2*tid+1);
        v0 = (1.f - aj0) + 1e-10f;
        v1 = (1.f - aj1) + 1e-10f;
        inc = v0 * v1;
        #pragma unroll
        for (int off=1; off<64; off<<=1) {
            float t = __shfl_up(inc, off, 64);
            if (lane >= off) inc *= t;
        }
        if (lane == 63) wtot[wv] = inc;
    }
    __syncthreads();

    float w0=0.f, w1=0.f;
    unsigned long long m0=0, m1=0;
    bool act0=false, act1=false;
    if (tid < 256) {
        float pre = 1.f;
        for (int i=0;i<wv;i++) pre *= wtot[i];
        float excl = __shfl_up(inc, 1, 64);
        if (lane == 0) excl = 1.f;
        float T0 = pre * excl;
        w0 = aj0 * T0;
        w1 = aj1 * T0 * v0;

        float rw = w0 + w1, rz = w0*zj0 + w1*zj1;
        #pragma unroll
        for (int off=32; off>0; off>>=1) { rw += __shfl_xor(rw,off,64); rz += __shfl_xor(rz,off,64); }
        if (lane == 0) { swsum[wv] = rw; sdep[wv] = rz; }

        act0 = (w0 > 1e-4f); act1 = (w1 > 1e-4f);
        m0 = __ballot(act0);
        m1 = __ballot(act1);
        int tot = __popcll(m0) + __popcll(m1);
        if (lane == 0) wcnt[wv] = tot;
    }
    __syncthreads();

    if (tid < 256) {
        int base = 0;
        for (int i=0;i<wv;i++) base += wcnt[i];
        unsigned long long below = (1ull<<lane)-1ull;
        int o = base + __popcll(m0 & below) + __popcll(m1 & below);
        int* tl = tmpl + r*NSAMP;
        float* tw = tmpw + r*NSAMP;
        if (act0) { tl[o] = (r<<9)|(2*tid);   tw[o] = w0; o++; }
        if (act1) { tl[o] = (r<<9)|(2*tid+1); tw[o] = w1; }

        if (tid == 0) {
            float a=0.f, b=0.f;
            #pragma unroll
            for (int i=0;i<4;i++){ a+=swsum[i]; b+=sdep[i]; }
            acc_out[r] = a; depth_out[r] = b;
            cnt[r] = wcnt[0]+wcnt[1]+wcnt[2]+wcnt[3];
        }
    }
}

// ---------------------------------------------------------------- k_compact (prefix fused: per-block prefix over cnt[], L2-hot)
__global__ __launch_bounds__(256) void k_compact(
    const int* __restrict__ tmpl, const float* __restrict__ tmpw,
    const int* __restrict__ cnt,
    int* __restrict__ basep, int* __restrict__ counter,
    int* __restrict__ list, float* __restrict__ wlist)
{
    int r = blockIdx.x;
    int tid = threadIdx.x, lane = tid & 63, wv = tid >> 6;

    int accb = 0, acct = 0;
    for (int i = tid; i < NRAYS; i += 256) {
        int c = cnt[i];
        acct += c;
        if (i < r) accb += c;
    }
    #pragma unroll
    for (int off=32; off>0; off>>=1) {
        accb += __shfl_xor(accb, off, 64);
        acct += __shfl_xor(acct, off, 64);
    }
    __shared__ int sb[4], st[4];
    if (lane == 0) { sb[wv] = accb; st[wv] = acct; }
    __syncthreads();
    int b = sb[0]+sb[1]+sb[2]+sb[3];
    int n = cnt[r];
    if (tid == 0) {
        basep[r] = b;
        if (r == 0) *counter = st[0]+st[1]+st[2]+st[3];
    }
    const int* tl = tmpl + r*NSAMP;
    const float* tw = tmpw + r*NSAMP;
    for (int j = tid; j < n; j += 256) {
        list[b+j]  = tl[j];
        wlist[b+j] = tw[j];
    }
}

// ---------------------------------------------------------------- k_gather: 8 threads/sample (6 active), grid-stride -> feat row (30 f32)
__global__ __launch_bounds__(256) void k_gather(
    const float* __restrict__ ro, const float* __restrict__ rd,
    const __half* __restrict__ apT0, const __half* __restrict__ apT1, const __half* __restrict__ apT2,
    const __half* __restrict__ alT0, const __half* __restrict__ alT1, const __half* __restrict__ alT2,
    const float* __restrict__ basis_w,
    const int* __restrict__ list, const int* __restrict__ counter,
    float* __restrict__ Xf)
{
    const float STEPF = (3.0f/299.0f)*0.5f;
    int count = *counter;
    int total = count * 8;
    for (int u = blockIdx.x*256 + threadIdx.x; u < total; u += gridDim.x*256) {
    int idx = u >> 3, q = u & 7;

    int sid = list[idx];
    int r = sid >> 9, s = sid & (NSAMP-1);
    float o0=ro[r*3+0], o1=ro[r*3+1], o2=ro[r*3+2];
    float d0=rd[r*3+0], d1=rd[r*3+1], d2=rd[r*3+2];
    float t_min = ray_tmin(o0,o1,o2,d0,d1,d2);
    float z = t_min + STEPF*(float)s;
    float xn[3] = { ((o0+d0*z)+1.5f)*(2.0f/3.0f)-1.0f,
                    ((o1+d1*z)+1.5f)*(2.0f/3.0f)-1.0f,
                    ((o2+d2*z)+1.5f)*(2.0f/3.0f)-1.0f };

    bool active = (q < 6);
    int i = min(q >> 1, 2);
    int h = q & 1;

    float c8[8];
    {
        const __half* apT[3]={apT0,apT1,apT2};
        const __half* alT[3]={alT0,alT1,alT2};
        const int M0[3]={0,0,1}, M1[3]={1,2,2}, V[3]={2,1,0};
        float fx = clampf((xn[M0[i]]*0.5f+0.5f)*299.f, 0.f, 299.f);
        float fy = clampf((xn[M1[i]]*0.5f+0.5f)*299.f, 0.f, 299.f);
        float ft = clampf((xn[V[i]] *0.5f+0.5f)*299.f, 0.f, 299.f);
        int x0=min((int)fx,298), y0=min((int)fy,298), i0=min((int)ft,298);
        float wx=fx-(float)x0, wy=fy-(float)y0, wt=ft-(float)i0;
        __half2 w00=__float2half2_rn((1.f-wx)*(1.f-wy)), w01=__float2half2_rn(wx*(1.f-wy));
        __half2 w10=__float2half2_rn((1.f-wx)*wy),       w11=__float2half2_rn(wx*wy);
        __half2 u0 =__float2half2_rn(1.f-wt),            u1 =__float2half2_rn(wt);
        if (active) {
            const __half* base = apT[i] + (size_t)(y0*GRIDN+x0)*16 + h*8;
            H8v a00 = *(const H8v*)(base);
            H8v a01 = *(const H8v*)(base + 16);
            H8v a10 = *(const H8v*)(base + GRIDN*16);
            H8v a11 = *(const H8v*)(base + GRIDN*16 + 16);
            const __half* lb = alT[i] + (size_t)i0*16 + h*8;
            H8v l0 = *(const H8v*)(lb);
            H8v l1 = *(const H8v*)(lb + 16);
            #pragma unroll
            for (int e=0;e<4;e++) {
                __half2 p = __hmul2(a00.h[e],w00);
                p = __hfma2(a01.h[e],w01,p);
                p = __hfma2(a10.h[e],w10,p);
                p = __hfma2(a11.h[e],w11,p);
                __half2 l = __hmul2(l0.h[e],u0);
                l = __hfma2(l1.h[e],u1,l);
                float2 c = __half22float2(__hmul2(p,l));
                c8[2*e]   = c.x;
                c8[2*e+1] = c.y;
            }
        } else {
            #pragma unroll
            for (int e=0;e<8;e++) c8[e] = 0.f;
        }
    }

    float kv[4] = {0.f, 0.f, 0.f, 0.f};
    #pragma unroll
    for (int j=0;j<27;j++) {
        const float4* b4 = (const float4*)(basis_w + j*48 + i*16 + h*8);
        float4 b0 = b4[0], b1 = b4[1];
        float p = b0.x*c8[0] + b0.y*c8[1] + b0.z*c8[2] + b0.w*c8[3]
                + b1.x*c8[4] + b1.y*c8[5] + b1.z*c8[6] + b1.w*c8[7];
        p += __shfl_xor(p, 1, 64);
        p += __shfl_xor(p, 2, 64);
        p += __shfl_xor(p, 4, 64);
        if (q == (j >> 2)) kv[j & 3] = p;
    }

    float4 v = make_float4(kv[0], kv[1], kv[2], kv[3]);
    if (q == 6) v.w = d0;
    if (q == 7) { v = make_float4(d1, d2, 0.f, 0.f); }
    *(float4*)&Xf[(size_t)idx*32 + q*4] = v;
    }
}

// ---------------------------------------------------------------- k_gemm: 32-sample tiles, double-buffered Xf prefetch (grid < ntiles)
#define XST 168
#define HST 136
#define TIL 32
#define XFS 36   // padded Xf_s stride

__global__ __launch_bounds__(512, 4) void k_gemm(
    const float* __restrict__ Xf,
    const unsigned short* __restrict__ w1b, const float* __restrict__ b1p,
    const unsigned short* __restrict__ w2b, const float* __restrict__ b2p,
    const float* __restrict__ w3p, const float* __restrict__ b3p,
    const float* __restrict__ wlist, const int* __restrict__ counter,
    __half* __restrict__ contrib)
{
    __shared__ __align__(16) unsigned short Xs[TIL*XST];   // X (bf16), later H2 (stride HST)
    __shared__ __align__(16) unsigned short Hs[TIL*HST];   // H1
    __shared__ __align__(16) float Xf_s[2][TIL][XFS];      // double-buffered feat+view staging

    int tid  = threadIdx.x;
    int wvid = tid >> 6, lane = tid & 63, ln15 = lane & 15, kq = lane >> 4;

    int count  = *counter;
    int ntiles = (count + TIL-1) >> 5;
    if ((int)blockIdx.x >= ntiles) return;

    int jrow = (wvid<<4) + ln15;
    bf16x8 w1f[5], w2f[4];
    #pragma unroll
    for (int ks=0; ks<5; ks++)
        w1f[ks] = *(const bf16x8*)&w1b[jrow*160 + ks*32 + kq*8];
    #pragma unroll
    for (int ks=0; ks<4; ks++)
        w2f[ks] = *(const bf16x8*)&w2b[jrow*128 + ks*32 + kq*8];
    float bias1 = b1p[jrow];
    float bias2 = b2p[jrow];

    int srow = tid >> 3, sq = tid & 7;   // stage-load role (first 256 threads)

    // ---- prologue: load first tile into buf 0
    int cur = 0;
    {
        if (tid < TIL*8) {
            int idx = blockIdx.x*TIL + srow;
            float4 v = make_float4(0.f,0.f,0.f,0.f);
            if (idx < count) v = *(const float4*)&Xf[(size_t)idx*32 + sq*4];
            *(float4*)&Xf_s[0][srow][sq*4] = v;
        }
        __syncthreads();
    }

    for (int t = blockIdx.x; t < ntiles; t += gridDim.x) {
        // ---- issue next tile's loads into registers (latency hides under this tile)
        int tn = t + gridDim.x;
        bool havepf = (tn < ntiles) && (tid < TIL*8);
        float4 pf = make_float4(0.f,0.f,0.f,0.f);
        if (havepf) {
            int idx = tn*TIL + srow;
            if (idx < count) pf = *(const float4*)&Xf[(size_t)idx*32 + sq*4];
        }

        // ---- stage 2: build X (bf16, posenc) -> Xs; uniform (row, j) units
        for (int u = tid; u < TIL*30; u += 512) {
            int row = u / 30, j = u - row*30;
            unsigned short* X = &Xs[row*XST];
            float f = Xf_s[cur][row][j];
            float s1 = __sinf(f), s2 = __sinf(2.f*f);
            float c1 = __cosf(f), c2 = __cosf(2.f*f);
            int c = j - 27;
            int o_s = (j < 27) ? (30 + 2*j) : (138 + 2*c);
            int o_c = (j < 27) ? (84 + 2*j) : (144 + 2*c);
            X[o_s]   = f2b(s1); X[o_s+1] = f2b(s2);
            X[o_c]   = f2b(c1); X[o_c+1] = f2b(c2);
            if ((j & 1) == 0) {               // packed dword write
                float fB = Xf_s[cur][row][j+1];
                unsigned pk = (unsigned)f2b(f) | ((unsigned)f2b(fB) << 16);
                *(unsigned*)&X[j] = pk;
            }
        }
        for (int u = tid; u < TIL*10; u += 512) {
            int row = u / 10, k = 150 + (u - row*10);
            Xs[row*XST + k] = 0;
        }
        __syncthreads();

        // ---- GEMM1 (MFMA): H1 = relu(X @ W1^T + b1); 2 M-tiles
        {
            f32x4 acc[2] = {};
            #pragma unroll
            for (int ks=0; ks<5; ks++) {
                int ko = ks*32 + kq*8;
                #pragma unroll
                for (int m=0;m<2;m++) {
                    bf16x8 a = *(const bf16x8*)&Xs[(m*16 + ln15)*XST + ko];
                    acc[m] = __builtin_amdgcn_mfma_f32_16x16x32_bf16(a, w1f[ks], acc[m], 0,0,0);
                }
            }
            int col = jrow;
            #pragma unroll
            for (int m=0;m<2;m++) {
                int rbase = m*16 + kq*4;
                #pragma unroll
                for (int j=0;j<4;j++)
                    Hs[(rbase+j)*HST + col] = f2b(fmaxf(acc[m][j] + bias1, 0.f));
            }
        }
        __syncthreads();

        // ---- GEMM2 (MFMA): H2 = relu(H1 @ W2^T + b2) -> Xs region (stride HST)
        {
            f32x4 acc[2] = {};
            #pragma unroll
            for (int ks=0; ks<4; ks++) {
                int ko = ks*32 + kq*8;
                #pragma unroll
                for (int m=0;m<2;m++) {
                    bf16x8 a = *(const bf16x8*)&Hs[(m*16 + ln15)*HST + ko];
                    acc[m] = __builtin_amdgcn_mfma_f32_16x16x32_bf16(a, w2f[ks], acc[m], 0,0,0);
                }
            }
            int col = jrow;
            #pragma unroll
            for (int m=0;m<2;m++) {
                int rbase = m*16 + kq*4;
                #pragma unroll
                for (int j=0;j<4;j++)
                    Xs[(rbase+j)*HST + col] = f2b(fmaxf(acc[m][j] + bias2, 0.f));
            }
        }
        __syncthreads();

        // ---- write prefetched tile into the other buffer (read next iteration)
        if (havepf)
            *(float4*)&Xf_s[cur^1][srow][sq*4] = pf;

        // ---- P5: rgb = sigmoid(H2 @ W3^T + b3); 6 threads/sample (ch x half),
        //      4-way ILP partial accumulators
        if (tid < TIL*8) {
            int u = tid >> 3, q = tid & 7;
            int idx = t*TIL + u;
            if (q < 6 && idx < count) {
                int ch = q >> 1, hf = q & 1;
                float wgt = wlist[idx];
                const unsigned short* h2 = Xs + u*HST + hf*64;
                const float* wr = w3p + ch*128 + hf*64;
                float pa[4] = {0.f, 0.f, 0.f, 0.f};
                #pragma unroll
                for (int kc=0;kc<8;kc++) {
                    bf16x8 hv = *(const bf16x8*)&h2[kc*8];
                    const float* wrk = wr + kc*8;
                    float tacc = 0.f;
                    #pragma unroll
                    for (int e=0;e<8;e++)
                        tacc += b2f((unsigned short)hv[e]) * wrk[e];
                    pa[kc & 3] += tacc;
                }
                float p = (pa[0] + pa[1]) + (pa[2] + pa[3]);
                p += __shfl_xor(p, 1, 64);
                if (hf == 0) {
                    float v = 0.f;
                    if (wgt > 0.f) {
                        float acc5 = b3p[ch] + p;
                        v = wgt * (1.f/(1.f + __expf(-acc5)));
                    }
                    contrib[(size_t)ch*CMAX + idx] = __float2half(v);
                }
            }
        }
        __syncthreads();
        cur ^= 1;
    }
}

// ---------------------------------------------------------------- k_rgbsum: per-ray contiguous reduce + finalize
__global__ __launch_bounds__(128) void k_rgbsum(
    const __half* __restrict__ contrib,
    const int* __restrict__ cnt, const int* __restrict__ basep,
    const float* __restrict__ acc_out, float* __restrict__ out)
{
    int r = blockIdx.x;
    int n = cnt[r], b = basep[r];
    int tid = threadIdx.x, lane = tid & 63, w = tid >> 6;
    float s0=0.f, s1=0.f, s2=0.f;
    for (int j = tid; j < n; j += 128) {
        s0 += __half2float(contrib[0*CMAX + b + j]);
        s1 += __half2float(contrib[1*CMAX + b + j]);
        s2 += __half2float(contrib[2*CMAX + b + j]);
    }
    #pragma unroll
    for (int off=32; off>0; off>>=1) {
        s0 += __shfl_xor(s0,off,64); s1 += __shfl_xor(s1,off,64); s2 += __shfl_xor(s2,off,64);
    }
    __shared__ float sh[3][2];
    if (lane == 0) { sh[0][w]=s0; sh[1][w]=s1; sh[2][w]=s2; }
    __syncthreads();
    if (tid == 0) {
        float bg = 1.f - acc_out[r];
        out[r*3+0] = clampf(sh[0][0]+sh[0][1] + bg, 0.f, 1.f);
        out[r*3+1] = clampf(sh[1][0]+sh[1][1] + bg, 0.f, 1.f);
        out[r*3+2] = clampf(sh[2][0]+sh[2][1] + bg, 0.f, 1.f);
    }
}

// ---------------------------------------------------------------- launch
extern "C" void kernel_launch(void* const* d_in, const int* in_sizes, int n_in,
                              void* d_out, int out_size, void* d_ws, size_t ws_size,
                              hipStream_t stream)
{
    const float* ro = (const float*)d_in[0];
    const float* rd = (const float*)d_in[1];
    const float* dplane[3] = {(const float*)d_in[2],(const float*)d_in[6],(const float*)d_in[10]};
    const float* dline[3]  = {(const float*)d_in[3],(const float*)d_in[7],(const float*)d_in[11]};
    const float* aplane[3] = {(const float*)d_in[4],(const float*)d_in[8],(const float*)d_in[12]};
    const float* aline[3]  = {(const float*)d_in[5],(const float*)d_in[9],(const float*)d_in[13]};
    const float* basis_w = (const float*)d_in[14];
    const float* w1 = (const float*)d_in[15];
    const float* b1 = (const float*)d_in[16];
    const float* w2 = (const float*)d_in[17];
    const float* b2 = (const float*)d_in[18];
    const float* w3 = (const float*)d_in[19];
    const float* b3 = (const float*)d_in[20];
    float* out = (float*)d_out;

    char* ws = (char*)d_ws;
    int*    counter  = (int*)   (ws + 0);
    float*  accb     = (float*) (ws + 12544);
    float*  wlist    = (float*) (ws + 16640);
    int*    list     = (int*)   (ws + 2113792);
    __half* planesT  = (__half*)(ws + 4210944);
    __half* linesT   = (__half*)(ws + 21490944);
    unsigned short* w1b = (unsigned short*)(ws + 21548544);
    unsigned short* w2b = (unsigned short*)(ws + 21589504);
    int*    cntb     = (int*)   (ws + 23719424);
    int*    baseb    = (int*)   (ws + 23723520);
    int*    tmpl     = (int*)   (ws + 23727616);
    float*  tmpw     = (float*) (ws + 25824768);
    __half* contrib  = (__half*)(ws + 23727616);   // overlays tmpl/tmpw after compact
    float*  Xf       = (float*) (ws + 27921920);

    // no memset needed: counter <- k_compact before any read

    TPtrs tp;
    for (int i=0;i<3;i++) {
        tp.psrc[i]   = dplane[i]; tp.pdst[i]   = planesT + (size_t)i*PLANE_ELEMS;
        tp.psrc[3+i] = aplane[i]; tp.pdst[3+i] = planesT + (size_t)(3+i)*PLANE_ELEMS;
        tp.lsrc[i]   = dline[i];  tp.ldst[i]   = linesT + i*(GRIDN*16);
        tp.lsrc[3+i] = aline[i];  tp.ldst[3+i] = linesT + (3+i)*(GRIDN*16);
    }
    dim3 tg((POS_ELEMS+255)/256, 7);   // by==6 slice runs fused weight prep
    hipLaunchKernelGGL(k_transpose, tg, dim3(256), 0, stream, tp, w1, w2, w1b, w2b);

    k_alphascan<<<NRAYS, 1024, 0, stream>>>(
        ro, rd,
        planesT + 0*(size_t)PLANE_ELEMS, planesT + 1*(size_t)PLANE_ELEMS, planesT + 2*(size_t)PLANE_ELEMS,
        linesT + 0*(GRIDN*16), linesT + 1*(GRIDN*16), linesT + 2*(GRIDN*16),
        accb, out + NRAYS*3, tmpl, tmpw, cntb);

    k_compact<<<NRAYS, 256, 0, stream>>>(tmpl, tmpw, cntb, baseb, counter, list, wlist);

    k_gather<<<4096, 256, 0, stream>>>(
        ro, rd,
        planesT + 3*(size_t)PLANE_ELEMS, planesT + 4*(size_t)PLANE_ELEMS, planesT + 5*(size_t)PLANE_ELEMS,
        linesT + 3*(GRIDN*16), linesT + 4*(GRIDN*16), linesT + 5*(GRIDN*16),
        basis_w, list, counter, Xf);

    k_gemm<<<512, 512, 0, stream>>>(
        Xf, w1b, b1, w2b, b2, w3, b3,
        wlist, counter, contrib);

    k_rgbsum<<<NRAYS, 128, 0, stream>>>(contrib, cntb, baseb, accb, out);
}

// Round 34
// 95.874 us; speedup vs baseline: 1.5298x; 1.5298x over previous
//
#include <hip/hip_runtime.h>
#include <hip/hip_fp16.h>
#include <math.h>

#define NRAYS 1024
#define NSAMP 512
#define GRIDN 300
#define POS_ELEMS (GRIDN*GRIDN)
#define PLANE_ELEMS (16*POS_ELEMS)
#define CMAX 524288

typedef short bf16x8 __attribute__((ext_vector_type(8)));
typedef short short8 __attribute__((ext_vector_type(8)));
typedef float f32x4  __attribute__((ext_vector_type(4)));

struct H8v { __half2 h[4]; };    // 8 fp16 = 16B

__device__ __forceinline__ float clampf(float x, float a, float b){ return fminf(fmaxf(x,a),b); }
__device__ __forceinline__ unsigned short f2b(float f){
    unsigned u = __builtin_bit_cast(unsigned, f);
    u = (u + 0x7FFFu + ((u>>16)&1u)) >> 16;
    return (unsigned short)u;
}
__device__ __forceinline__ float b2f(unsigned short h){
    unsigned u = ((unsigned)h) << 16;
    return __builtin_bit_cast(float, u);
}

__device__ __forceinline__ float ray_tmin(float o0,float o1,float o2,float d0,float d1,float d2){
    float v0=(d0==0.f)?1e-6f:d0, v1=(d1==0.f)?1e-6f:d1, v2=(d2==0.f)?1e-6f:d2;
    float t_min = -1e30f, a, b;
    a=(1.5f-o0)/v0; b=(-1.5f-o0)/v0; t_min=fmaxf(t_min,fminf(a,b));
    a=(1.5f-o1)/v1; b=(-1.5f-o1)/v1; t_min=fmaxf(t_min,fminf(a,b));
    a=(1.5f-o2)/v2; b=(-1.5f-o2)/v2; t_min=fmaxf(t_min,fminf(a,b));
    return clampf(t_min, 2.0f, 6.0f);
}

// ---------------------------------------------------------------- transpose: planes/lines -> channel-last fp16; by==6 slice does weight prep
struct TPtrs {
    const float* psrc[6]; __half* pdst[6];
    const float* lsrc[6]; __half* ldst[6];
};

__global__ __launch_bounds__(256) void k_transpose(TPtrs tp,
    const float* __restrict__ w1, const float* __restrict__ w2,
    unsigned short* __restrict__ w1b, unsigned short* __restrict__ w2b)
{
    int by  = blockIdx.y;
    if (by == 6) {                 // fused weight prep (144 blocks active)
        int idx = blockIdx.x * 256 + threadIdx.x;
        if (idx < 128*160) {
            int j = idx / 160, k = idx - j*160;
            w1b[idx] = (k < 150) ? f2b(w1[j*150 + k]) : 0;
        } else if (idx < 128*160 + 128*128) {
            int i2 = idx - 128*160;
            w2b[i2] = f2b(w2[i2]);
        }
        return;
    }
    int pos = blockIdx.x * 256 + threadIdx.x;
    if (pos < POS_ELEMS) {
        const float* src = tp.psrc[by];
        __half2 o[8];
        #pragma unroll
        for (int e = 0; e < 8; e++) {
            float a = src[(2*e  ) * POS_ELEMS + pos];
            float b = src[(2*e+1) * POS_ELEMS + pos];
            o[e] = __float22half2_rn(make_float2(a,b));
        }
        float4* dst = (float4*)(tp.pdst[by] + (size_t)pos * 16);
        dst[0] = *(float4*)&o[0];
        dst[1] = *(float4*)&o[4];
    }
    if (pos < GRIDN) {
        const float* ls = tp.lsrc[by];
        __half*      ld = tp.ldst[by];
        #pragma unroll
        for (int c = 0; c < 16; c++) ld[pos * 16 + c] = __float2half_rn(ls[c * GRIDN + pos]);
    }
}

// ---------------------------------------------------------------- k_alphascan: alpha (1024 thr: sample x half) + per-ray scan/compaction fused
__global__ __launch_bounds__(1024) void k_alphascan(
    const float* __restrict__ ro, const float* __restrict__ rd,
    const __half* __restrict__ dpT0, const __half* __restrict__ dpT1, const __half* __restrict__ dpT2,
    const __half* __restrict__ dlT0, const __half* __restrict__ dlT1, const __half* __restrict__ dlT2,
    float* __restrict__ acc_out, float* __restrict__ depth_out,
    int* __restrict__ tmpl, float* __restrict__ tmpw, int* __restrict__ cnt)
{
    const float STEPF = (3.0f/299.0f)*0.5f;
    int r = blockIdx.x;
    int tid = threadIdx.x;
    int s = tid >> 1, h = tid & 1;

    __shared__ float alpha_s[NSAMP];
    __shared__ float wtot[4], swsum[4], sdep[4];
    __shared__ int   wcnt[4];

    float o0=ro[r*3+0], o1=ro[r*3+1], o2=ro[r*3+2];
    float d0=rd[r*3+0], d1=rd[r*3+1], d2=rd[r*3+2];
    float t_min = ray_tmin(o0,o1,o2,d0,d1,d2);

    // ---- alpha phase (all 1024 threads; 2 threads per sample = channel halves)
    {
        float z  = t_min + STEPF * (float)s;
        float p0 = o0 + d0*z, p1 = o1 + d1*z, p2 = o2 + d2*z;
        bool valid = (p0>=-1.5f)&&(p0<=1.5f)&&(p1>=-1.5f)&&(p1<=1.5f)&&(p2>=-1.5f)&&(p2<=1.5f);

        float sfp = 0.f;
        if (valid) {
            float xn[3] = { (p0+1.5f)*(2.0f/3.0f)-1.0f,
                            (p1+1.5f)*(2.0f/3.0f)-1.0f,
                            (p2+1.5f)*(2.0f/3.0f)-1.0f };
            const __half* dpT[3] = {dpT0,dpT1,dpT2};
            const __half* dlT[3] = {dlT0,dlT1,dlT2};
            const int M0[3]={0,0,1}, M1[3]={1,2,2}, V[3]={2,1,0};
            #pragma unroll
            for (int i=0;i<3;i++) {
                float fx = clampf((xn[M0[i]]*0.5f+0.5f)*299.f, 0.f, 299.f);
                float fy = clampf((xn[M1[i]]*0.5f+0.5f)*299.f, 0.f, 299.f);
                float ft = clampf((xn[V[i]] *0.5f+0.5f)*299.f, 0.f, 299.f);
                int x0=min((int)fx,298), y0=min((int)fy,298), i0=min((int)ft,298);
                float wx=fx-(float)x0, wy=fy-(float)y0, wt=ft-(float)i0;
                __half2 w00=__float2half2_rn((1.f-wx)*(1.f-wy)), w01=__float2half2_rn(wx*(1.f-wy));
                __half2 w10=__float2half2_rn((1.f-wx)*wy),       w11=__float2half2_rn(wx*wy);
                __half2 u0 =__float2half2_rn(1.f-wt),            u1 =__float2half2_rn(wt);
                const __half* base = dpT[i] + (size_t)(y0*GRIDN+x0)*16 + h*8;
                H8v a00 = *(const H8v*)(base);
                H8v a01 = *(const H8v*)(base + 16);
                H8v a10 = *(const H8v*)(base + GRIDN*16);
                H8v a11 = *(const H8v*)(base + GRIDN*16 + 16);
                const __half* lb = dlT[i] + (size_t)i0*16 + h*8;
                H8v l0 = *(const H8v*)(lb);
                H8v l1 = *(const H8v*)(lb + 16);
                #pragma unroll
                for (int e=0;e<4;e++) {
                    __half2 p = __hmul2(a00.h[e],w00);
                    p = __hfma2(a01.h[e],w01,p);
                    p = __hfma2(a10.h[e],w10,p);
                    p = __hfma2(a11.h[e],w11,p);
                    __half2 l = __hmul2(l0.h[e],u0);
                    l = __hfma2(l1.h[e],u1,l);
                    float2 c = __half22float2(__hmul2(p,l));
                    sfp += c.x + c.y;
                }
            }
        }
        float sf = sfp + __shfl_xor(sfp, 1, 64);   // combine halves (adjacent lanes)
        if (h == 0) {
            float sig = 0.f;
            if (valid) {
                float xs = sf - 10.0f;
                sig = fmaxf(xs, 0.f) + __logf(1.f + __expf(-fabsf(xs)));   // softplus
            }
            alpha_s[s] = (s < NSAMP-1) ? (1.f - __expf(-sig * (STEPF*25.0f))) : 0.f;
        }
    }
    __syncthreads();

    // ---- scan phase (first 256 threads; barriers are block-wide)
    int lane = tid & 63, wv = tid >> 6;
    float aj0=0.f, aj1=0.f, zj0=0.f, zj1=0.f, inc=1.f, v0=1.f, v1=1.f;
    if (tid < 256) {
        aj0 = alpha_s[2*tid]; aj1 = alpha_s[2*tid+1];
        zj0 = t_min + STEPF * (float)(2*tid);
        zj1 = t_min + STEPF * (float)(2*tid+1);
        v0 = (1.f - aj0) + 1e-10f;
        v1 = (1.f - aj1) + 1e-10f;
        inc = v0 * v1;
        #pragma unroll
        for (int off=1; off<64; off<<=1) {
            float t = __shfl_up(inc, off, 64);
            if (lane >= off) inc *= t;
        }
        if (lane == 63) wtot[wv] = inc;
    }
    __syncthreads();

    float w0=0.f, w1=0.f;
    unsigned long long m0=0, m1=0;
    bool act0=false, act1=false;
    if (tid < 256) {
        float pre = 1.f;
        for (int i=0;i<wv;i++) pre *= wtot[i];
        float excl = __shfl_up(inc, 1, 64);
        if (lane == 0) excl = 1.f;
        float T0 = pre * excl;
        w0 = aj0 * T0;
        w1 = aj1 * T0 * v0;

        float rw = w0 + w1, rz = w0*zj0 + w1*zj1;
        #pragma unroll
        for (int off=32; off>0; off>>=1) { rw += __shfl_xor(rw,off,64); rz += __shfl_xor(rz,off,64); }
        if (lane == 0) { swsum[wv] = rw; sdep[wv] = rz; }

        act0 = (w0 > 1e-4f); act1 = (w1 > 1e-4f);
        m0 = __ballot(act0);
        m1 = __ballot(act1);
        int tot = __popcll(m0) + __popcll(m1);
        if (lane == 0) wcnt[wv] = tot;
    }
    __syncthreads();

    if (tid < 256) {
        int base = 0;
        for (int i=0;i<wv;i++) base += wcnt[i];
        unsigned long long below = (1ull<<lane)-1ull;
        int o = base + __popcll(m0 & below) + __popcll(m1 & below);
        int* tl = tmpl + r*NSAMP;
        float* tw = tmpw + r*NSAMP;
        if (act0) { tl[o] = (r<<9)|(2*tid);   tw[o] = w0; o++; }
        if (act1) { tl[o] = (r<<9)|(2*tid+1); tw[o] = w1; }

        if (tid == 0) {
            float a=0.f, b=0.f;
            #pragma unroll
            for (int i=0;i<4;i++){ a+=swsum[i]; b+=sdep[i]; }
            acc_out[r] = a; depth_out[r] = b;
            cnt[r] = wcnt[0]+wcnt[1]+wcnt[2]+wcnt[3];
        }
    }
}

// ---------------------------------------------------------------- k_compact (prefix fused: per-block prefix over cnt[], L2-hot)
__global__ __launch_bounds__(256) void k_compact(
    const int* __restrict__ tmpl, const float* __restrict__ tmpw,
    const int* __restrict__ cnt,
    int* __restrict__ basep, int* __restrict__ counter,
    int* __restrict__ list, float* __restrict__ wlist)
{
    int r = blockIdx.x;
    int tid = threadIdx.x, lane = tid & 63, wv = tid >> 6;

    int accb = 0, acct = 0;
    for (int i = tid; i < NRAYS; i += 256) {
        int c = cnt[i];
        acct += c;
        if (i < r) accb += c;
    }
    #pragma unroll
    for (int off=32; off>0; off>>=1) {
        accb += __shfl_xor(accb, off, 64);
        acct += __shfl_xor(acct, off, 64);
    }
    __shared__ int sb[4], st[4];
    if (lane == 0) { sb[wv] = accb; st[wv] = acct; }
    __syncthreads();
    int b = sb[0]+sb[1]+sb[2]+sb[3];
    int n = cnt[r];
    if (tid == 0) {
        basep[r] = b;
        if (r == 0) *counter = st[0]+st[1]+st[2]+st[3];
    }
    const int* tl = tmpl + r*NSAMP;
    const float* tw = tmpw + r*NSAMP;
    for (int j = tid; j < n; j += 256) {
        list[b+j]  = tl[j];
        wlist[b+j] = tw[j];
    }
}

// ---------------------------------------------------------------- k_gather: 8 threads/sample (6 active), fixed grid, early return
__global__ __launch_bounds__(256) void k_gather(
    const float* __restrict__ ro, const float* __restrict__ rd,
    const __half* __restrict__ apT0, const __half* __restrict__ apT1, const __half* __restrict__ apT2,
    const __half* __restrict__ alT0, const __half* __restrict__ alT1, const __half* __restrict__ alT2,
    const float* __restrict__ basis_w,
    const int* __restrict__ list, const int* __restrict__ counter,
    float* __restrict__ Xf)
{
    const float STEPF = (3.0f/299.0f)*0.5f;
    int gid = blockIdx.x*256 + threadIdx.x;
    int idx = gid >> 3, q = gid & 7;
    int count = *counter;
    if (idx >= count) return;

    int sid = list[idx];
    int r = sid >> 9, s = sid & (NSAMP-1);
    float o0=ro[r*3+0], o1=ro[r*3+1], o2=ro[r*3+2];
    float d0=rd[r*3+0], d1=rd[r*3+1], d2=rd[r*3+2];
    float t_min = ray_tmin(o0,o1,o2,d0,d1,d2);
    float z = t_min + STEPF*(float)s;
    float xn[3] = { ((o0+d0*z)+1.5f)*(2.0f/3.0f)-1.0f,
                    ((o1+d1*z)+1.5f)*(2.0f/3.0f)-1.0f,
                    ((o2+d2*z)+1.5f)*(2.0f/3.0f)-1.0f };

    bool active = (q < 6);
    int i = min(q >> 1, 2);
    int h = q & 1;

    float c8[8];
    {
        const __half* apT[3]={apT0,apT1,apT2};
        const __half* alT[3]={alT0,alT1,alT2};
        const int M0[3]={0,0,1}, M1[3]={1,2,2}, V[3]={2,1,0};
        float fx = clampf((xn[M0[i]]*0.5f+0.5f)*299.f, 0.f, 299.f);
        float fy = clampf((xn[M1[i]]*0.5f+0.5f)*299.f, 0.f, 299.f);
        float ft = clampf((xn[V[i]] *0.5f+0.5f)*299.f, 0.f, 299.f);
        int x0=min((int)fx,298), y0=min((int)fy,298), i0=min((int)ft,298);
        float wx=fx-(float)x0, wy=fy-(float)y0, wt=ft-(float)i0;
        __half2 w00=__float2half2_rn((1.f-wx)*(1.f-wy)), w01=__float2half2_rn(wx*(1.f-wy));
        __half2 w10=__float2half2_rn((1.f-wx)*wy),       w11=__float2half2_rn(wx*wy);
        __half2 u0 =__float2half2_rn(1.f-wt),            u1 =__float2half2_rn(wt);
        if (active) {
            const __half* base = apT[i] + (size_t)(y0*GRIDN+x0)*16 + h*8;
            H8v a00 = *(const H8v*)(base);
            H8v a01 = *(const H8v*)(base + 16);
            H8v a10 = *(const H8v*)(base + GRIDN*16);
            H8v a11 = *(const H8v*)(base + GRIDN*16 + 16);
            const __half* lb = alT[i] + (size_t)i0*16 + h*8;
            H8v l0 = *(const H8v*)(lb);
            H8v l1 = *(const H8v*)(lb + 16);
            #pragma unroll
            for (int e=0;e<4;e++) {
                __half2 p = __hmul2(a00.h[e],w00);
                p = __hfma2(a01.h[e],w01,p);
                p = __hfma2(a10.h[e],w10,p);
                p = __hfma2(a11.h[e],w11,p);
                __half2 l = __hmul2(l0.h[e],u0);
                l = __hfma2(l1.h[e],u1,l);
                float2 c = __half22float2(__hmul2(p,l));
                c8[2*e]   = c.x;
                c8[2*e+1] = c.y;
            }
        } else {
            #pragma unroll
            for (int e=0;e<8;e++) c8[e] = 0.f;
        }
    }

    float kv[4] = {0.f, 0.f, 0.f, 0.f};
    #pragma unroll
    for (int j=0;j<27;j++) {
        const float4* b4 = (const float4*)(basis_w + j*48 + i*16 + h*8);
        float4 b0 = b4[0], b1 = b4[1];
        float p = b0.x*c8[0] + b0.y*c8[1] + b0.z*c8[2] + b0.w*c8[3]
                + b1.x*c8[4] + b1.y*c8[5] + b1.z*c8[6] + b1.w*c8[7];
        p += __shfl_xor(p, 1, 64);
        p += __shfl_xor(p, 2, 64);
        p += __shfl_xor(p, 4, 64);
        if (q == (j >> 2)) kv[j & 3] = p;
    }

    float4 v = make_float4(kv[0], kv[1], kv[2], kv[3]);
    if (q == 6) v.w = d0;
    if (q == 7) { v = make_float4(d1, d2, 0.f, 0.f); }
    *(float4*)&Xf[(size_t)idx*32 + q*4] = v;
}

// ---------------------------------------------------------------- k_gemm: 32-sample tiles, double-buffered Xf prefetch (grid < ntiles)
#define XST 168
#define HST 136
#define TIL 32
#define XFS 36   // padded Xf_s stride

__global__ __launch_bounds__(512, 4) void k_gemm(
    const float* __restrict__ Xf,
    const unsigned short* __restrict__ w1b, const float* __restrict__ b1p,
    const unsigned short* __restrict__ w2b, const float* __restrict__ b2p,
    const float* __restrict__ w3p, const float* __restrict__ b3p,
    const float* __restrict__ wlist, const int* __restrict__ counter,
    __half* __restrict__ contrib)
{
    __shared__ __align__(16) unsigned short Xs[TIL*XST];   // X (bf16), later H2 (stride HST)
    __shared__ __align__(16) unsigned short Hs[TIL*HST];   // H1
    __shared__ __align__(16) float Xf_s[2][TIL][XFS];      // double-buffered feat+view staging

    int tid  = threadIdx.x;
    int wvid = tid >> 6, lane = tid & 63, ln15 = lane & 15, kq = lane >> 4;

    int count  = *counter;
    int ntiles = (count + TIL-1) >> 5;
    if ((int)blockIdx.x >= ntiles) return;

    int jrow = (wvid<<4) + ln15;
    bf16x8 w1f[5], w2f[4];
    #pragma unroll
    for (int ks=0; ks<5; ks++)
        w1f[ks] = *(const bf16x8*)&w1b[jrow*160 + ks*32 + kq*8];
    #pragma unroll
    for (int ks=0; ks<4; ks++)
        w2f[ks] = *(const bf16x8*)&w2b[jrow*128 + ks*32 + kq*8];
    float bias1 = b1p[jrow];
    float bias2 = b2p[jrow];

    int srow = tid >> 3, sq = tid & 7;   // stage-load role (first 256 threads)

    // ---- prologue: load first tile into buf 0
    int cur = 0;
    {
        if (tid < TIL*8) {
            int idx = blockIdx.x*TIL + srow;
            float4 v = make_float4(0.f,0.f,0.f,0.f);
            if (idx < count) v = *(const float4*)&Xf[(size_t)idx*32 + sq*4];
            *(float4*)&Xf_s[0][srow][sq*4] = v;
        }
        __syncthreads();
    }

    for (int t = blockIdx.x; t < ntiles; t += gridDim.x) {
        // ---- issue next tile's loads into registers (latency hides under this tile)
        int tn = t + gridDim.x;
        bool havepf = (tn < ntiles) && (tid < TIL*8);
        float4 pf = make_float4(0.f,0.f,0.f,0.f);
        if (havepf) {
            int idx = tn*TIL + srow;
            if (idx < count) pf = *(const float4*)&Xf[(size_t)idx*32 + sq*4];
        }

        // ---- stage 2: build X (bf16, posenc) -> Xs; uniform (row, j) units
        for (int u = tid; u < TIL*30; u += 512) {
            int row = u / 30, j = u - row*30;
            unsigned short* X = &Xs[row*XST];
            float f = Xf_s[cur][row][j];
            float s1 = __sinf(f), s2 = __sinf(2.f*f);
            float c1 = __cosf(f), c2 = __cosf(2.f*f);
            int c = j - 27;
            int o_s = (j < 27) ? (30 + 2*j) : (138 + 2*c);
            int o_c = (j < 27) ? (84 + 2*j) : (144 + 2*c);
            X[o_s]   = f2b(s1); X[o_s+1] = f2b(s2);
            X[o_c]   = f2b(c1); X[o_c+1] = f2b(c2);
            if ((j & 1) == 0) {               // packed dword write
                float fB = Xf_s[cur][row][j+1];
                unsigned pk = (unsigned)f2b(f) | ((unsigned)f2b(fB) << 16);
                *(unsigned*)&X[j] = pk;
            }
        }
        for (int u = tid; u < TIL*10; u += 512) {
            int row = u / 10, k = 150 + (u - row*10);
            Xs[row*XST + k] = 0;
        }
        __syncthreads();

        // ---- GEMM1 (MFMA): H1 = relu(X @ W1^T + b1); 2 M-tiles
        {
            f32x4 acc[2] = {};
            #pragma unroll
            for (int ks=0; ks<5; ks++) {
                int ko = ks*32 + kq*8;
                #pragma unroll
                for (int m=0;m<2;m++) {
                    bf16x8 a = *(const bf16x8*)&Xs[(m*16 + ln15)*XST + ko];
                    acc[m] = __builtin_amdgcn_mfma_f32_16x16x32_bf16(a, w1f[ks], acc[m], 0,0,0);
                }
            }
            int col = jrow;
            #pragma unroll
            for (int m=0;m<2;m++) {
                int rbase = m*16 + kq*4;
                #pragma unroll
                for (int j=0;j<4;j++)
                    Hs[(rbase+j)*HST + col] = f2b(fmaxf(acc[m][j] + bias1, 0.f));
            }
        }
        __syncthreads();

        // ---- GEMM2 (MFMA): H2 = relu(H1 @ W2^T + b2) -> Xs region (stride HST)
        {
            f32x4 acc[2] = {};
            #pragma unroll
            for (int ks=0; ks<4; ks++) {
                int ko = ks*32 + kq*8;
                #pragma unroll
                for (int m=0;m<2;m++) {
                    bf16x8 a = *(const bf16x8*)&Hs[(m*16 + ln15)*HST + ko];
                    acc[m] = __builtin_amdgcn_mfma_f32_16x16x32_bf16(a, w2f[ks], acc[m], 0,0,0);
                }
            }
            int col = jrow;
            #pragma unroll
            for (int m=0;m<2;m++) {
                int rbase = m*16 + kq*4;
                #pragma unroll
                for (int j=0;j<4;j++)
                    Xs[(rbase+j)*HST + col] = f2b(fmaxf(acc[m][j] + bias2, 0.f));
            }
        }
        __syncthreads();

        // ---- write prefetched tile into the other buffer (read next iteration)
        if (havepf)
            *(float4*)&Xf_s[cur^1][srow][sq*4] = pf;

        // ---- P5: rgb = sigmoid(H2 @ W3^T + b3); 6 threads/sample (ch x half),
        //      4-way ILP partial accumulators
        if (tid < TIL*8) {
            int u = tid >> 3, q = tid & 7;
            int idx = t*TIL + u;
            if (q < 6 && idx < count) {
                int ch = q >> 1, hf = q & 1;
                float wgt = wlist[idx];
                const unsigned short* h2 = Xs + u*HST + hf*64;
                const float* wr = w3p + ch*128 + hf*64;
                float pa[4] = {0.f, 0.f, 0.f, 0.f};
                #pragma unroll
                for (int kc=0;kc<8;kc++) {
                    bf16x8 hv = *(const bf16x8*)&h2[kc*8];
                    const float* wrk = wr + kc*8;
                    float tacc = 0.f;
                    #pragma unroll
                    for (int e=0;e<8;e++)
                        tacc += b2f((unsigned short)hv[e]) * wrk[e];
                    pa[kc & 3] += tacc;
                }
                float p = (pa[0] + pa[1]) + (pa[2] + pa[3]);
                p += __shfl_xor(p, 1, 64);
                if (hf == 0) {
                    float v = 0.f;
                    if (wgt > 0.f) {
                        float acc5 = b3p[ch] + p;
                        v = wgt * (1.f/(1.f + __expf(-acc5)));
                    }
                    contrib[(size_t)ch*CMAX + idx] = __float2half(v);
                }
            }
        }
        __syncthreads();
        cur ^= 1;
    }
}

// ---------------------------------------------------------------- k_rgbsum: per-ray contiguous reduce + finalize
__global__ __launch_bounds__(128) void k_rgbsum(
    const __half* __restrict__ contrib,
    const int* __restrict__ cnt, const int* __restrict__ basep,
    const float* __restrict__ acc_out, float* __restrict__ out)
{
    int r = blockIdx.x;
    int n = cnt[r], b = basep[r];
    int tid = threadIdx.x, lane = tid & 63, w = tid >> 6;
    float s0=0.f, s1=0.f, s2=0.f;
    for (int j = tid; j < n; j += 128) {
        s0 += __half2float(contrib[0*CMAX + b + j]);
        s1 += __half2float(contrib[1*CMAX + b + j]);
        s2 += __half2float(contrib[2*CMAX + b + j]);
    }
    #pragma unroll
    for (int off=32; off>0; off>>=1) {
        s0 += __shfl_xor(s0,off,64); s1 += __shfl_xor(s1,off,64); s2 += __shfl_xor(s2,off,64);
    }
    __shared__ float sh[3][2];
    if (lane == 0) { sh[0][w]=s0; sh[1][w]=s1; sh[2][w]=s2; }
    __syncthreads();
    if (tid == 0) {
        float bg = 1.f - acc_out[r];
        out[r*3+0] = clampf(sh[0][0]+sh[0][1] + bg, 0.f, 1.f);
        out[r*3+1] = clampf(sh[1][0]+sh[1][1] + bg, 0.f, 1.f);
        out[r*3+2] = clampf(sh[2][0]+sh[2][1] + bg, 0.f, 1.f);
    }
}

// ---------------------------------------------------------------- launch
extern "C" void kernel_launch(void* const* d_in, const int* in_sizes, int n_in,
                              void* d_out, int out_size, void* d_ws, size_t ws_size,
                              hipStream_t stream)
{
    const float* ro = (const float*)d_in[0];
    const float* rd = (const float*)d_in[1];
    const float* dplane[3] = {(const float*)d_in[2],(const float*)d_in[6],(const float*)d_in[10]};
    const float* dline[3]  = {(const float*)d_in[3],(const float*)d_in[7],(const float*)d_in[11]};
    const float* aplane[3] = {(const float*)d_in[4],(const float*)d_in[8],(const float*)d_in[12]};
    const float* aline[3]  = {(const float*)d_in[5],(const float*)d_in[9],(const float*)d_in[13]};
    const float* basis_w = (const float*)d_in[14];
    const float* w1 = (const float*)d_in[15];
    const float* b1 = (const float*)d_in[16];
    const float* w2 = (const float*)d_in[17];
    const float* b2 = (const float*)d_in[18];
    const float* w3 = (const float*)d_in[19];
    const float* b3 = (const float*)d_in[20];
    float* out = (float*)d_out;

    char* ws = (char*)d_ws;
    int*    counter  = (int*)   (ws + 0);
    float*  accb     = (float*) (ws + 12544);
    float*  wlist    = (float*) (ws + 16640);
    int*    list     = (int*)   (ws + 2113792);
    __half* planesT  = (__half*)(ws + 4210944);
    __half* linesT   = (__half*)(ws + 21490944);
    unsigned short* w1b = (unsigned short*)(ws + 21548544);
    unsigned short* w2b = (unsigned short*)(ws + 21589504);
    int*    cntb     = (int*)   (ws + 23719424);
    int*    baseb    = (int*)   (ws + 23723520);
    int*    tmpl     = (int*)   (ws + 23727616);
    float*  tmpw     = (float*) (ws + 25824768);
    __half* contrib  = (__half*)(ws + 23727616);   // overlays tmpl/tmpw after compact
    float*  Xf       = (float*) (ws + 27921920);

    // no memset needed: counter <- k_compact before any read

    TPtrs tp;
    for (int i=0;i<3;i++) {
        tp.psrc[i]   = dplane[i]; tp.pdst[i]   = planesT + (size_t)i*PLANE_ELEMS;
        tp.psrc[3+i] = aplane[i]; tp.pdst[3+i] = planesT + (size_t)(3+i)*PLANE_ELEMS;
        tp.lsrc[i]   = dline[i];  tp.ldst[i]   = linesT + i*(GRIDN*16);
        tp.lsrc[3+i] = aline[i];  tp.ldst[3+i] = linesT + (3+i)*(GRIDN*16);
    }
    dim3 tg((POS_ELEMS+255)/256, 7);   // by==6 slice runs fused weight prep
    hipLaunchKernelGGL(k_transpose, tg, dim3(256), 0, stream, tp, w1, w2, w1b, w2b);

    k_alphascan<<<NRAYS, 1024, 0, stream>>>(
        ro, rd,
        planesT + 0*(size_t)PLANE_ELEMS, planesT + 1*(size_t)PLANE_ELEMS, planesT + 2*(size_t)PLANE_ELEMS,
        linesT + 0*(GRIDN*16), linesT + 1*(GRIDN*16), linesT + 2*(GRIDN*16),
        accb, out + NRAYS*3, tmpl, tmpw, cntb);

    k_compact<<<NRAYS, 256, 0, stream>>>(tmpl, tmpw, cntb, baseb, counter, list, wlist);

    k_gather<<<(CMAX*8)/256, 256, 0, stream>>>(
        ro, rd,
        planesT + 3*(size_t)PLANE_ELEMS, planesT + 4*(size_t)PLANE_ELEMS, planesT + 5*(size_t)PLANE_ELEMS,
        linesT + 3*(GRIDN*16), linesT + 4*(GRIDN*16), linesT + 5*(GRIDN*16),
        basis_w, list, counter, Xf);

    k_gemm<<<512, 512, 0, stream>>>(
        Xf, w1b, b1, w2b, b2, w3, b3,
        wlist, counter, contrib);

    k_rgbsum<<<NRAYS, 128, 0, stream>>>(contrib, cntb, baseb, accb, out);
}